// Round 4
// baseline (150.588 us; speedup 1.0000x reference)
//
#include <hip/hip_runtime.h>
#include <hip/hip_bf16.h>

typedef int int4v __attribute__((ext_vector_type(4)));

#define K_DIM 2048
#define N_DIM 2048
#define M_DIM 16384
#define NW 4194304   // weight element count (2048*2048)
#define BKB 128      // K-step bytes per row (128 i8 elements)
#define NKT (K_DIM / BKB)   // 16 K-tiles

// ---------------- w_scale: deterministic 2-stage f64 abs-mean ----------------
__global__ void k_wsum(const float4* __restrict__ w4, double* __restrict__ red) {
  const int n4 = NW / 4;
  double s = 0.0;
  for (int i = blockIdx.x * blockDim.x + threadIdx.x; i < n4; i += gridDim.x * blockDim.x) {
    float4 v = w4[i];
    s += (double)fabsf(v.x) + (double)fabsf(v.y) + (double)fabsf(v.z) + (double)fabsf(v.w);
  }
  for (int o = 32; o; o >>= 1) s += __shfl_xor(s, o);
  __shared__ double sd[4];
  if ((threadIdx.x & 63) == 0) sd[threadIdx.x >> 6] = s;
  __syncthreads();
  if (threadIdx.x == 0) red[blockIdx.x] = (sd[0] + sd[1]) + (sd[2] + sd[3]);
}

__global__ void k_wscale(const double* __restrict__ red, double* __restrict__ wsd) {
  double s = red[threadIdx.x];                 // 256 threads, parallel
  for (int o = 32; o; o >>= 1) s += __shfl_xor(s, o);
  __shared__ double sd[4];
  if ((threadIdx.x & 63) == 0) sd[threadIdx.x >> 6] = s;
  __syncthreads();
  if (threadIdx.x == 0) {
    double m = ((sd[0] + sd[1]) + (sd[2] + sd[3])) / (double)NW;
    *wsd = (m > 1e-6) ? m : 1e-6;
  }
}

// ---------------- weight ternary quant -> int8 {-1,0,1} ----------------
__device__ __forceinline__ char wq1(float v, double ws) {
  double r = rint((double)v / ws);          // round-half-even, matches np.round
  r = fmin(fmax(r, -1.0), 1.0);
  return (char)(int)r;
}

__global__ void k_wquant(const float4* __restrict__ w4, const double* __restrict__ wsd,
                         char4* __restrict__ wq4) {
  int i = blockIdx.x * blockDim.x + threadIdx.x;
  if (i >= NW / 4) return;
  double ws = *wsd;
  float4 v = w4[i];
  char4 q;
  q.x = wq1(v.x, ws);
  q.y = wq1(v.y, ws);
  q.z = wq1(v.z, ws);
  q.w = wq1(v.w, ws);
  wq4[i] = q;
}

// ---------------- per-token absmax + int8 absmax quant ----------------
__device__ __forceinline__ char qi8(float v, double rr) {
  double q = rint((double)v * rr);
  q = fmin(fmax(q, -127.0), 127.0);
  return (char)(int)q;
}

__global__ void k_xquant(const float* __restrict__ x, float* __restrict__ ascale,
                         char* __restrict__ xq) {
  const int row = blockIdx.x;
  const int t = threadIdx.x;
  const float4* xr = (const float4*)(x + (size_t)row * K_DIM);
  float4 v0 = xr[t];
  float4 v1 = xr[t + 256];
  float m = fmaxf(fmaxf(fmaxf(fabsf(v0.x), fabsf(v0.y)), fmaxf(fabsf(v0.z), fabsf(v0.w))),
                  fmaxf(fmaxf(fabsf(v1.x), fabsf(v1.y)), fmaxf(fabsf(v1.z), fabsf(v1.w))));
  for (int o = 32; o; o >>= 1) m = fmaxf(m, __shfl_xor(m, o));
  __shared__ float sm[4];
  if ((t & 63) == 0) sm[t >> 6] = m;
  __syncthreads();
  float a = fmaxf(fmaxf(sm[0], sm[1]), fmaxf(sm[2], sm[3]));
  a = fmaxf(a, 1e-8f);
  if (t == 0) ascale[row] = a;
  double rr = 127.0 / (double)a;
  char4* qr4 = (char4*)(xq + (size_t)row * K_DIM);
  char4 a4, b4;
  a4.x = qi8(v0.x, rr); a4.y = qi8(v0.y, rr); a4.z = qi8(v0.z, rr); a4.w = qi8(v0.w, rr);
  b4.x = qi8(v1.x, rr); b4.y = qi8(v1.y, rr); b4.z = qi8(v1.z, rr); b4.w = qi8(v1.w, rr);
  qr4[t] = a4;
  qr4[t + 256] = b4;
}

// ---------------- GEMM: 256x256 tile, 8 waves, pipelined frag reads ----------
__device__ __forceinline__ void gload16(const void* g, void* l) {
  __builtin_amdgcn_global_load_lds(
      (const __attribute__((address_space(1))) void*)g,
      (__attribute__((address_space(3))) void*)l, 16, 0, 0);
}

// frag reads: plain derefs -> compiler emits counted lgkmcnt (no hard fences)
#define RD_A(DST, CA, MH, CO)                                               \
  _Pragma("unroll") for (int mf = 0; mf < 4; ++mf)                          \
    DST[mf] = *(const int4v*)((CA) + (rA + (MH)*64 + mf * 16) * 128 + (CO));

#define RD_B(DST, CB, CO)                                                   \
  _Pragma("unroll") for (int nf = 0; nf < 4; ++nf)                          \
    DST[nf] = *(const int4v*)((CB) + (rB + nf * 16) * 128 + (CO));

#define MM(MH, AF, BF)                                                      \
  __builtin_amdgcn_s_setprio(1);                                            \
  _Pragma("unroll") for (int mf = 0; mf < 4; ++mf)                          \
  _Pragma("unroll") for (int nf = 0; nf < 4; ++nf)                          \
    acc[(MH)*4 + mf][nf] = __builtin_amdgcn_mfma_i32_16x16x64_i8(           \
        AF[mf], BF[nf], acc[(MH)*4 + mf][nf], 0, 0, 0);                     \
  __builtin_amdgcn_s_setprio(0);

// one K-tile: gate + single barrier, stage next tile, 4 MFMA phases with
// next-phase reads issued ahead of each MFMA cluster
#define KTILE(KT, CA, CB, NA, NB, DOSTAGE)                                  \
  {                                                                         \
    asm volatile("s_waitcnt vmcnt(0)" ::: "memory");                        \
    __builtin_amdgcn_s_barrier();                                           \
    asm volatile("" ::: "memory");                                          \
    if (DOSTAGE) {                                                          \
      const char* An = Ab + ((KT) + 1) * BKB;                               \
      const char* Bn = Bb + ((KT) + 1) * BKB;                               \
      _Pragma("unroll") for (int c = 0; c < 4; ++c)                         \
        gload16(An + soff[c], (NA) + loff[c]);                              \
      _Pragma("unroll") for (int c = 0; c < 4; ++c)                         \
        gload16(Bn + soff[c], (NB) + loff[c]);                              \
    }                                                                       \
    RD_A(afA, CA, 0, co0);                                                  \
    RD_B(bfA, CB, co0);                                                     \
    RD_A(afB, CA, 1, co0);   /* ph1 frags in flight during ph0 MFMA */      \
    MM(0, afA, bfA);                                                        \
    RD_A(afA, CA, 0, co1);   /* ph2 frags */                                \
    RD_B(bfB, CB, co1);                                                     \
    MM(1, afB, bfA);                                                        \
    RD_A(afB, CA, 1, co1);   /* ph3 frags */                                \
    MM(0, afA, bfB);                                                        \
    MM(1, afB, bfB);                                                        \
  }

__global__ __launch_bounds__(512, 2) void k_gemm(
    const char* __restrict__ xq, const char* __restrict__ wq,
    const float* __restrict__ ascale, const double* __restrict__ wsd,
    float* __restrict__ out) {
  __shared__ __align__(16) char lds[131072];
  char* lA0 = lds;            // 32 KB
  char* lB0 = lds + 32768;
  char* lA1 = lds + 65536;
  char* lB1 = lds + 98304;

  const int tid = threadIdx.x;
  const int l = tid & 63;
  const int wv = tid >> 6;        // 0..7
  const int wm = wv >> 2;         // M half
  const int wn = wv & 3;          // N quarter
  const int g = l >> 4, r16 = l & 15;

  // XCD-aware bijective swizzle: 512 blocks = 8 xcd * 64 chunk
  const int bid = blockIdx.x;
  const int logical = (bid & 7) * 64 + (bid >> 3);
  const int br = logical >> 3;    // 0..63  (M blocks)
  const int bc = logical & 7;     // 0..7   (N blocks)

  const char* Ab = xq + (size_t)br * 256 * K_DIM;
  const char* Bb = wq + (size_t)bc * 256 * K_DIM;

  // staging: LDS dest linear (global_load_lds constraint), source pre-swizzled
  int soff[4], loff[4];
#pragma unroll
  for (int c = 0; c < 4; ++c) {
    int lb = c * 8192 + tid * 16;
    loff[c] = lb;
    int row = lb >> 7;
    int cb = lb & 127;
    soff[c] = row * K_DIM + (cb ^ ((row & 7) << 4));
  }

  // read-side swizzled column offsets (row&7 == r16&7 for all fragment rows)
  const int sw = (r16 & 7) << 4;
  const int co0 = (g * 16) ^ sw;        // k-slice 0
  const int co1 = (64 + g * 16) ^ sw;   // k-slice 1
  const int rA = wm * 128 + r16;
  const int rB = wn * 64 + r16;

  int4v acc[8][4];
#pragma unroll
  for (int mf = 0; mf < 8; ++mf)
#pragma unroll
    for (int nf = 0; nf < 4; ++nf) acc[mf][nf] = (int4v){0, 0, 0, 0};

  // prologue: stage tile 0 into buf0
#pragma unroll
  for (int c = 0; c < 4; ++c) gload16(Ab + soff[c], lA0 + loff[c]);
#pragma unroll
  for (int c = 0; c < 4; ++c) gload16(Bb + soff[c], lB0 + loff[c]);

  int4v afA[4], afB[4], bfA[4], bfB[4];

  for (int kt = 0; kt < NKT; kt += 2) {
    KTILE(kt,     lA0, lB0, lA1, lB1, true);
    KTILE(kt + 1, lA1, lB1, lA0, lB0, (kt + 2 < NKT));
  }

  // epilogue: y = acc * w_scale * (a_scale[t]/127); |acc| <= 127*2048 < 2^24 exact
  float wsf = (float)(*wsd);
  size_t trow0 = (size_t)br * 256 + wm * 128;
  int oc0 = bc * 256 + wn * 64;
#pragma unroll
  for (int mf = 0; mf < 8; ++mf) {
#pragma unroll
    for (int j = 0; j < 4; ++j) {
      size_t t = trow0 + mf * 16 + g * 4 + j;  // C/D: col=lane&15, row=(lane>>4)*4+reg
      float s = wsf * (ascale[t] / 127.0f);
      float* yr = out + t * (size_t)N_DIM + oc0;
#pragma unroll
      for (int nf = 0; nf < 4; ++nf) yr[nf * 16 + r16] = (float)acc[mf][nf][j] * s;
    }
  }
}

extern "C" void kernel_launch(void* const* d_in, const int* in_sizes, int n_in,
                              void* d_out, int out_size, void* d_ws, size_t ws_size,
                              hipStream_t stream) {
  const float* x = (const float*)d_in[0];
  const float* w = (const float*)d_in[1];
  float* out = (float*)d_out;

  char* ws = (char*)d_ws;
  double* red = (double*)ws;                               // 256 * 8 B
  double* wsd = (double*)(ws + 2048);                      // 1 double
  float* ascale = (float*)(ws + 4096);                     // 16384 floats
  char* xq = (char*)(ws + 4096 + 65536);                   // 32 MiB
  char* wq = xq + (size_t)M_DIM * K_DIM;                   // 4 MiB

  k_wsum<<<256, 256, 0, stream>>>((const float4*)w, red);
  k_wscale<<<1, 256, 0, stream>>>(red, wsd);
  k_wquant<<<NW / 4 / 256, 256, 0, stream>>>((const float4*)w, wsd, (char4*)wq);
  k_xquant<<<M_DIM, 256, 0, stream>>>(x, ascale, xq);
  k_gemm<<<dim3(N_DIM / 256 * M_DIM / 256), 512, 0, stream>>>(xq, wq, ascale, wsd, out);
}

// Round 5
// 128.191 us; speedup vs baseline: 1.1747x; 1.1747x over previous
//
#include <hip/hip_runtime.h>
#include <hip/hip_bf16.h>

typedef int int4v __attribute__((ext_vector_type(4)));

#define K_DIM 2048
#define N_DIM 2048
#define M_DIM 16384
#define NW 4194304   // weight element count (2048*2048)
#define BKB 128      // K-step bytes per row (128 i8 elements)
#define NKT (K_DIM / BKB)   // 16 K-tiles

// ---------------- w_scale: deterministic 2-stage f64 abs-mean ----------------
__global__ void k_wsum(const float4* __restrict__ w4, double* __restrict__ red) {
  const int n4 = NW / 4;
  double s = 0.0;
  for (int i = blockIdx.x * blockDim.x + threadIdx.x; i < n4; i += gridDim.x * blockDim.x) {
    float4 v = w4[i];
    s += (double)fabsf(v.x) + (double)fabsf(v.y) + (double)fabsf(v.z) + (double)fabsf(v.w);
  }
  for (int o = 32; o; o >>= 1) s += __shfl_xor(s, o);
  __shared__ double sd[4];
  if ((threadIdx.x & 63) == 0) sd[threadIdx.x >> 6] = s;
  __syncthreads();
  if (threadIdx.x == 0) red[blockIdx.x] = (sd[0] + sd[1]) + (sd[2] + sd[3]);
}

__global__ void k_wscale(const double* __restrict__ red, double* __restrict__ wsd) {
  double s = red[threadIdx.x];                 // 256 threads, parallel
  for (int o = 32; o; o >>= 1) s += __shfl_xor(s, o);
  __shared__ double sd[4];
  if ((threadIdx.x & 63) == 0) sd[threadIdx.x >> 6] = s;
  __syncthreads();
  if (threadIdx.x == 0) {
    double m = ((sd[0] + sd[1]) + (sd[2] + sd[3])) / (double)NW;
    *wsd = (m > 1e-6) ? m : 1e-6;
  }
}

// ---------------- weight ternary quant -> int8 {-1,0,1} ----------------
__device__ __forceinline__ char wq1(float v, double ws) {
  double r = rint((double)v / ws);          // round-half-even, matches np.round
  r = fmin(fmax(r, -1.0), 1.0);
  return (char)(int)r;
}

__global__ void k_wquant(const float4* __restrict__ w4, const double* __restrict__ wsd,
                         char4* __restrict__ wq4) {
  int i = blockIdx.x * blockDim.x + threadIdx.x;
  if (i >= NW / 4) return;
  double ws = *wsd;
  float4 v = w4[i];
  char4 q;
  q.x = wq1(v.x, ws);
  q.y = wq1(v.y, ws);
  q.z = wq1(v.z, ws);
  q.w = wq1(v.w, ws);
  wq4[i] = q;
}

// ---------------- per-token absmax + int8 absmax quant ----------------
__device__ __forceinline__ char qi8(float v, double rr) {
  double q = rint((double)v * rr);
  q = fmin(fmax(q, -127.0), 127.0);
  return (char)(int)q;
}

__global__ void k_xquant(const float* __restrict__ x, float* __restrict__ ascale,
                         char* __restrict__ xq) {
  const int row = blockIdx.x;
  const int t = threadIdx.x;
  const float4* xr = (const float4*)(x + (size_t)row * K_DIM);
  float4 v0 = xr[t];
  float4 v1 = xr[t + 256];
  float m = fmaxf(fmaxf(fmaxf(fabsf(v0.x), fabsf(v0.y)), fmaxf(fabsf(v0.z), fabsf(v0.w))),
                  fmaxf(fmaxf(fabsf(v1.x), fabsf(v1.y)), fmaxf(fabsf(v1.z), fabsf(v1.w))));
  for (int o = 32; o; o >>= 1) m = fmaxf(m, __shfl_xor(m, o));
  __shared__ float sm[4];
  if ((t & 63) == 0) sm[t >> 6] = m;
  __syncthreads();
  float a = fmaxf(fmaxf(sm[0], sm[1]), fmaxf(sm[2], sm[3]));
  a = fmaxf(a, 1e-8f);
  if (t == 0) ascale[row] = a;
  double rr = 127.0 / (double)a;
  char4* qr4 = (char4*)(xq + (size_t)row * K_DIM);
  char4 a4, b4;
  a4.x = qi8(v0.x, rr); a4.y = qi8(v0.y, rr); a4.z = qi8(v0.z, rr); a4.w = qi8(v0.w, rr);
  b4.x = qi8(v1.x, rr); b4.y = qi8(v1.y, rr); b4.z = qi8(v1.z, rr); b4.w = qi8(v1.w, rr);
  qr4[t] = a4;
  qr4[t + 256] = b4;
}

// ---------------- GEMM: 256x256 tile, 8 waves, m201-style dual-barrier phases
__device__ __forceinline__ void gload16(const void* g, void* l) {
  __builtin_amdgcn_global_load_lds(
      (const __attribute__((address_space(1))) void*)g,
      (__attribute__((address_space(3))) void*)l, 16, 0, 0);
}

#define RD_A(DST, CA, MH, CO)                                               \
  _Pragma("unroll") for (int mf = 0; mf < 4; ++mf)                          \
    DST[mf] = *(const int4v*)((CA) + (rA + (MH)*64 + mf * 16) * 128 + (CO));

#define RD_B(DST, CB, CO)                                                   \
  _Pragma("unroll") for (int nf = 0; nf < 4; ++nf)                          \
    DST[nf] = *(const int4v*)((CB) + (rB + nf * 16) * 128 + (CO));

#define MM(MH, AF, BF)                                                      \
  __builtin_amdgcn_s_setprio(1);                                            \
  _Pragma("unroll") for (int mf = 0; mf < 4; ++mf)                          \
  _Pragma("unroll") for (int nf = 0; nf < 4; ++nf)                          \
    acc[(MH)*4 + mf][nf] = __builtin_amdgcn_mfma_i32_16x16x64_i8(           \
        AF[mf], BF[nf], acc[(MH)*4 + mf][nf], 0, 0, 0);                     \
  __builtin_amdgcn_s_setprio(0);

#define CFENCE asm volatile("" ::: "memory")
#define BAR    do { CFENCE; __builtin_amdgcn_s_barrier(); CFENCE; } while (0)
#define LGKM0  do { asm volatile("s_waitcnt lgkmcnt(0)" ::: "memory");      \
                    __builtin_amdgcn_sched_barrier(0); } while (0)

// One K-tile = 4 phases, each [reads|stage] BAR lgkm0 MFMA BAR.
// Staging front-loaded (A in ph0, B in ph1) so the ph3 vmcnt(0) gates loads
// issued >=2 phases earlier: race-free by construction and ~free.
#define KTILE(KT, CA, CB, NA, NB)                                           \
  {                                                                         \
    const char* An = Ab + (((KT) + 1) & (NKT - 1)) * BKB;                   \
    const char* Bn = Bb + (((KT) + 1) & (NKT - 1)) * BKB;                   \
    /* ---- ph0: frags(MH0,k0) + stage A(next) ---- */                      \
    RD_A(afA, CA, 0, co0);                                                  \
    RD_B(bfA, CB, co0);                                                     \
    _Pragma("unroll") for (int c = 0; c < 4; ++c)                           \
      gload16(An + soff[c], (NA) + loff[c]);                                \
    BAR; LGKM0;                                                             \
    MM(0, afA, bfA);                                                        \
    BAR;                                                                    \
    /* ---- ph1: frags(MH1,k0) + stage B(next); reuse bfA ---- */           \
    RD_A(afB, CA, 1, co0);                                                  \
    _Pragma("unroll") for (int c = 0; c < 4; ++c)                           \
      gload16(Bn + soff[c], (NB) + loff[c]);                                \
    BAR; LGKM0;                                                             \
    MM(1, afB, bfA);                                                        \
    BAR;                                                                    \
    /* ---- ph2: frags(MH0,k1) ---- */                                      \
    RD_A(afA, CA, 0, co1);                                                  \
    RD_B(bfB, CB, co1);                                                     \
    BAR; LGKM0;                                                             \
    MM(0, afA, bfB);                                                        \
    BAR;                                                                    \
    /* ---- ph3: frags(MH1,k1); gate next tile's staging ---- */            \
    RD_A(afB, CA, 1, co1);                                                  \
    BAR; LGKM0;                                                             \
    MM(1, afB, bfB);                                                        \
    asm volatile("s_waitcnt vmcnt(0)" ::: "memory");                        \
    BAR;                                                                    \
  }

__global__ __launch_bounds__(512, 1) void k_gemm(
    const char* __restrict__ xq, const char* __restrict__ wq,
    const float* __restrict__ ascale, const double* __restrict__ wsd,
    float* __restrict__ out) {
  __shared__ __align__(16) char lds[131072];
  char* lA0 = lds;            // 32 KB
  char* lB0 = lds + 32768;
  char* lA1 = lds + 65536;
  char* lB1 = lds + 98304;

  const int tid = threadIdx.x;
  const int l = tid & 63;
  const int wv = tid >> 6;        // 0..7
  const int wm = wv >> 2;         // M half
  const int wn = wv & 3;          // N quarter
  const int g = l >> 4, r16 = l & 15;

  // XCD-aware bijective swizzle: 512 blocks = 8 xcd * 64 chunk
  const int bid = blockIdx.x;
  const int logical = (bid & 7) * 64 + (bid >> 3);
  const int br = logical >> 3;    // 0..63  (M blocks)
  const int bc = logical & 7;     // 0..7   (N blocks)

  const char* Ab = xq + (size_t)br * 256 * K_DIM;
  const char* Bb = wq + (size_t)bc * 256 * K_DIM;

  // staging: LDS dest linear (global_load_lds constraint), source pre-swizzled
  int soff[4], loff[4];
#pragma unroll
  for (int c = 0; c < 4; ++c) {
    int lb = c * 8192 + tid * 16;
    loff[c] = lb;
    int row = lb >> 7;
    int cb = lb & 127;
    soff[c] = row * K_DIM + (cb ^ ((row & 7) << 4));
  }

  // read-side swizzled column offsets (row&7 == r16&7 for all fragment rows)
  const int sw = (r16 & 7) << 4;
  const int co0 = (g * 16) ^ sw;        // k-slice 0
  const int co1 = (64 + g * 16) ^ sw;   // k-slice 1
  const int rA = wm * 128 + r16;
  const int rB = wn * 64 + r16;

  int4v acc[8][4];
#pragma unroll
  for (int mf = 0; mf < 8; ++mf)
#pragma unroll
    for (int nf = 0; nf < 4; ++nf) acc[mf][nf] = (int4v){0, 0, 0, 0};

  // prologue: stage tile 0 into buf0, drain, sync
#pragma unroll
  for (int c = 0; c < 4; ++c) gload16(Ab + soff[c], lA0 + loff[c]);
#pragma unroll
  for (int c = 0; c < 4; ++c) gload16(Bb + soff[c], lB0 + loff[c]);
  asm volatile("s_waitcnt vmcnt(0)" ::: "memory");
  BAR;

  int4v afA[4], afB[4], bfA[4], bfB[4];

  for (int kt = 0; kt < NKT; kt += 2) {
    KTILE(kt,     lA0, lB0, lA1, lB1);
    KTILE(kt + 1, lA1, lB1, lA0, lB0);
  }

  // epilogue: y = acc * w_scale * (a_scale[t]/127); |acc| <= 127*2048 < 2^24 exact
  float wsf = (float)(*wsd);
  size_t trow0 = (size_t)br * 256 + wm * 128;
  int oc0 = bc * 256 + wn * 64;
#pragma unroll
  for (int mf = 0; mf < 8; ++mf) {
#pragma unroll
    for (int j = 0; j < 4; ++j) {
      size_t t = trow0 + mf * 16 + g * 4 + j;  // C/D: col=lane&15, row=(lane>>4)*4+reg
      float s = wsf * (ascale[t] / 127.0f);
      float* yr = out + t * (size_t)N_DIM + oc0;
#pragma unroll
      for (int nf = 0; nf < 4; ++nf) yr[nf * 16 + r16] = (float)acc[mf][nf][j] * s;
    }
  }
}

extern "C" void kernel_launch(void* const* d_in, const int* in_sizes, int n_in,
                              void* d_out, int out_size, void* d_ws, size_t ws_size,
                              hipStream_t stream) {
  const float* x = (const float*)d_in[0];
  const float* w = (const float*)d_in[1];
  float* out = (float*)d_out;

  char* ws = (char*)d_ws;
  double* red = (double*)ws;                               // 256 * 8 B
  double* wsd = (double*)(ws + 2048);                      // 1 double
  float* ascale = (float*)(ws + 4096);                     // 16384 floats
  char* xq = (char*)(ws + 4096 + 65536);                   // 32 MiB
  char* wq = xq + (size_t)M_DIM * K_DIM;                   // 4 MiB

  k_wsum<<<256, 256, 0, stream>>>((const float4*)w, red);
  k_wscale<<<1, 256, 0, stream>>>(red, wsd);
  k_wquant<<<NW / 4 / 256, 256, 0, stream>>>((const float4*)w, wsd, (char4*)wq);
  k_xquant<<<M_DIM, 256, 0, stream>>>(x, ascale, xq);
  k_gemm<<<dim3(N_DIM / 256 * M_DIM / 256), 512, 0, stream>>>(xq, wq, ascale, wsd, out);
}

// Round 6
// 127.445 us; speedup vs baseline: 1.1816x; 1.0059x over previous
//
#include <hip/hip_runtime.h>
#include <hip/hip_bf16.h>

typedef int int4v __attribute__((ext_vector_type(4)));

#define K_DIM 2048
#define N_DIM 2048
#define M_DIM 16384
#define NW 4194304   // weight element count (2048*2048)
#define BKB 128      // K-step bytes per row (128 i8 elements)
#define NKT (K_DIM / BKB)   // 16 K-tiles

// ---------------- w_scale: deterministic 2-stage f64 abs-mean ----------------
__global__ void k_wsum(const float4* __restrict__ w4, double* __restrict__ red) {
  const int n4 = NW / 4;
  double s = 0.0;
  for (int i = blockIdx.x * blockDim.x + threadIdx.x; i < n4; i += gridDim.x * blockDim.x) {
    float4 v = w4[i];
    s += (double)fabsf(v.x) + (double)fabsf(v.y) + (double)fabsf(v.z) + (double)fabsf(v.w);
  }
  for (int o = 32; o; o >>= 1) s += __shfl_xor(s, o);
  __shared__ double sd[4];
  if ((threadIdx.x & 63) == 0) sd[threadIdx.x >> 6] = s;
  __syncthreads();
  if (threadIdx.x == 0) red[blockIdx.x] = (sd[0] + sd[1]) + (sd[2] + sd[3]);
}

__global__ void k_wscale(const double* __restrict__ red, double* __restrict__ wsd) {
  double s = red[threadIdx.x];                 // 256 threads, parallel
  for (int o = 32; o; o >>= 1) s += __shfl_xor(s, o);
  __shared__ double sd[4];
  if ((threadIdx.x & 63) == 0) sd[threadIdx.x >> 6] = s;
  __syncthreads();
  if (threadIdx.x == 0) {
    double m = ((sd[0] + sd[1]) + (sd[2] + sd[3])) / (double)NW;
    *wsd = (m > 1e-6) ? m : 1e-6;
  }
}

// ---------------- weight ternary quant -> int8 {-1,0,1} ----------------
__device__ __forceinline__ char wq1(float v, double ws) {
  double r = rint((double)v / ws);          // round-half-even, matches np.round
  r = fmin(fmax(r, -1.0), 1.0);
  return (char)(int)r;
}

__global__ void k_wquant(const float4* __restrict__ w4, const double* __restrict__ wsd,
                         char4* __restrict__ wq4) {
  int i = blockIdx.x * blockDim.x + threadIdx.x;
  if (i >= NW / 4) return;
  double ws = *wsd;
  float4 v = w4[i];
  char4 q;
  q.x = wq1(v.x, ws);
  q.y = wq1(v.y, ws);
  q.z = wq1(v.z, ws);
  q.w = wq1(v.w, ws);
  wq4[i] = q;
}

// ---------------- per-token absmax + int8 absmax quant ----------------
__device__ __forceinline__ char qi8(float v, double rr) {
  double q = rint((double)v * rr);
  q = fmin(fmax(q, -127.0), 127.0);
  return (char)(int)q;
}

__global__ void k_xquant(const float* __restrict__ x, float* __restrict__ ascale,
                         char* __restrict__ xq) {
  const int row = blockIdx.x;
  const int t = threadIdx.x;
  const float4* xr = (const float4*)(x + (size_t)row * K_DIM);
  float4 v0 = xr[t];
  float4 v1 = xr[t + 256];
  float m = fmaxf(fmaxf(fmaxf(fabsf(v0.x), fabsf(v0.y)), fmaxf(fabsf(v0.z), fabsf(v0.w))),
                  fmaxf(fmaxf(fabsf(v1.x), fabsf(v1.y)), fmaxf(fabsf(v1.z), fabsf(v1.w))));
  for (int o = 32; o; o >>= 1) m = fmaxf(m, __shfl_xor(m, o));
  __shared__ float sm[4];
  if ((t & 63) == 0) sm[t >> 6] = m;
  __syncthreads();
  float a = fmaxf(fmaxf(sm[0], sm[1]), fmaxf(sm[2], sm[3]));
  a = fmaxf(a, 1e-8f);
  if (t == 0) ascale[row] = a;
  double rr = 127.0 / (double)a;
  char4* qr4 = (char4*)(xq + (size_t)row * K_DIM);
  char4 a4, b4;
  a4.x = qi8(v0.x, rr); a4.y = qi8(v0.y, rr); a4.z = qi8(v0.z, rr); a4.w = qi8(v0.w, rr);
  b4.x = qi8(v1.x, rr); b4.y = qi8(v1.y, rr); b4.z = qi8(v1.z, rr); b4.w = qi8(v1.w, rr);
  qr4[t] = a4;
  qr4[t + 256] = b4;
}

// ---------------- GEMM: 256x256 tile, 8 waves, one-window register pipeline --
__device__ __forceinline__ void gload16(const void* g, void* l) {
  __builtin_amdgcn_global_load_lds(
      (const __attribute__((address_space(1))) void*)g,
      (__attribute__((address_space(3))) void*)l, 16, 0, 0);
}

#define RD_A(DST, CA, MH, CO)                                               \
  _Pragma("unroll") for (int mf = 0; mf < 4; ++mf)                          \
    DST[mf] = *(const int4v*)((CA) + (rA + (MH)*64 + mf * 16) * 128 + (CO));

#define RD_B(DST, CB, CO)                                                   \
  _Pragma("unroll") for (int nf = 0; nf < 4; ++nf)                          \
    DST[nf] = *(const int4v*)((CB) + (rB + nf * 16) * 128 + (CO));

#define MM(MH, AF, BF)                                                      \
  __builtin_amdgcn_s_setprio(1);                                            \
  _Pragma("unroll") for (int mf = 0; mf < 4; ++mf)                          \
  _Pragma("unroll") for (int nf = 0; nf < 4; ++nf)                          \
    acc[(MH)*4 + mf][nf] = __builtin_amdgcn_mfma_i32_16x16x64_i8(           \
        AF[mf], BF[nf], acc[(MH)*4 + mf][nf], 0, 0, 0);                     \
  __builtin_amdgcn_s_setprio(0);

#define CFENCE asm volatile("" ::: "memory")
#define BAR    do { CFENCE; __builtin_amdgcn_s_barrier(); CFENCE; } while (0)

// One K-tile = 4 windows. Each window: issue NEXT window's frag reads (into the
// spare register set), then barrier, then MFMA on the CURRENT set. The MFMA's
// operands were read one window earlier -> compiler's counted lgkm wait is
// already satisfied -> the fresh reads' LDS service overlaps the MFMA drain.
#define TILE(CA, CB, NA, NB, KT)                                            \
  {                                                                         \
    const char* An = Ab + (((KT) + 1) & (NKT - 1)) * BKB;                   \
    const char* Bn = Bb + (((KT) + 1) & (NKT - 1)) * BKB;                   \
    /* w0: CUR=(MH0,co0: afX,bfP) | read afY(MH1,co0) | stage A(next) */    \
    RD_A(afY, CA, 1, co0);                                                  \
    _Pragma("unroll") for (int c = 0; c < 4; ++c)                           \
      gload16(An + soff[c], (NA) + loff[c]);                                \
    BAR;                                                                    \
    MM(0, afX, bfP);                                                        \
    BAR;                                                                    \
    /* w1: CUR=(MH1,co0: afY,bfP) | read afX,bfQ (co1) | stage B(next) */   \
    RD_A(afX, CA, 0, co1);                                                  \
    RD_B(bfQ, CB, co1);                                                     \
    _Pragma("unroll") for (int c = 0; c < 4; ++c)                           \
      gload16(Bn + soff[c], (NB) + loff[c]);                                \
    BAR;                                                                    \
    MM(1, afY, bfP);                                                        \
    BAR;                                                                    \
    /* w2: CUR=(MH0,co1: afX,bfQ) | read afY(MH1,co1) */                    \
    RD_A(afY, CA, 1, co1);                                                  \
    BAR;                                                                    \
    MM(0, afX, bfQ);                                                        \
    BAR;                                                                    \
    /* w3: CUR=(MH1,co1: afY,bfQ) | gate next tile, read its w0 frags */    \
    asm volatile("s_waitcnt vmcnt(0)" ::: "memory");                        \
    BAR;   /* all waves' staging of next tile visible to all */             \
    RD_A(afX, NA, 0, co0);                                                  \
    RD_B(bfP, NB, co0);                                                     \
    MM(1, afY, bfQ);                                                        \
    BAR;                                                                    \
  }

__global__ __launch_bounds__(512, 1) void k_gemm(
    const char* __restrict__ xq, const char* __restrict__ wq,
    const float* __restrict__ ascale, const double* __restrict__ wsd,
    float* __restrict__ out) {
  __shared__ __align__(16) char lds[131072];
  char* lA0 = lds;            // 32 KB
  char* lB0 = lds + 32768;
  char* lA1 = lds + 65536;
  char* lB1 = lds + 98304;

  const int tid = threadIdx.x;
  const int l = tid & 63;
  const int wv = tid >> 6;        // 0..7
  const int wm = wv >> 2;         // M half
  const int wn = wv & 3;          // N quarter
  const int g = l >> 4, r16 = l & 15;

  // XCD-aware bijective swizzle: 512 blocks = 8 xcd * 64 chunk
  const int bid = blockIdx.x;
  const int logical = (bid & 7) * 64 + (bid >> 3);
  const int br = logical >> 3;    // 0..63  (M blocks)
  const int bc = logical & 7;     // 0..7   (N blocks)

  const char* Ab = xq + (size_t)br * 256 * K_DIM;
  const char* Bb = wq + (size_t)bc * 256 * K_DIM;

  // staging: LDS dest linear (global_load_lds constraint), source pre-swizzled
  int soff[4], loff[4];
#pragma unroll
  for (int c = 0; c < 4; ++c) {
    int lb = c * 8192 + tid * 16;
    loff[c] = lb;
    int row = lb >> 7;
    int cb = lb & 127;
    soff[c] = row * K_DIM + (cb ^ ((row & 7) << 4));
  }

  // read-side swizzled column offsets (row&7 == r16&7 for all fragment rows)
  const int sw = (r16 & 7) << 4;
  const int co0 = (g * 16) ^ sw;        // k-slice 0
  const int co1 = (64 + g * 16) ^ sw;   // k-slice 1
  const int rA = wm * 128 + r16;
  const int rB = wn * 64 + r16;

  int4v acc[8][4];
#pragma unroll
  for (int mf = 0; mf < 8; ++mf)
#pragma unroll
    for (int nf = 0; nf < 4; ++nf) acc[mf][nf] = (int4v){0, 0, 0, 0};

  // prologue: stage tile 0 into buf0, drain, sync, preload first frag set
#pragma unroll
  for (int c = 0; c < 4; ++c) gload16(Ab + soff[c], lA0 + loff[c]);
#pragma unroll
  for (int c = 0; c < 4; ++c) gload16(Bb + soff[c], lB0 + loff[c]);
  asm volatile("s_waitcnt vmcnt(0)" ::: "memory");
  BAR;

  int4v afA0[4], afA1[4], bfB0[4], bfB1[4];
  // naming: afX=afA0, afY=afA1, bfP=bfB0, bfQ=bfB1
#define afX afA0
#define afY afA1
#define bfP bfB0
#define bfQ bfB1

  RD_A(afX, lA0, 0, co0);
  RD_B(bfP, lB0, co0);

  for (int kt = 0; kt < NKT; kt += 2) {
    TILE(lA0, lB0, lA1, lB1, kt);
    TILE(lA1, lB1, lA0, lB0, kt + 1);
  }

  // epilogue: y = acc * w_scale * (a_scale[t]/127); |acc| <= 127*2048 < 2^24 exact
  float wsf = (float)(*wsd);
  size_t trow0 = (size_t)br * 256 + wm * 128;
  int oc0 = bc * 256 + wn * 64;
#pragma unroll
  for (int mf = 0; mf < 8; ++mf) {
#pragma unroll
    for (int j = 0; j < 4; ++j) {
      size_t t = trow0 + mf * 16 + g * 4 + j;  // C/D: col=lane&15, row=(lane>>4)*4+reg
      float s = wsf * (ascale[t] / 127.0f);
      float* yr = out + t * (size_t)N_DIM + oc0;
#pragma unroll
      for (int nf = 0; nf < 4; ++nf) yr[nf * 16 + r16] = (float)acc[mf][nf][j] * s;
    }
  }
}

extern "C" void kernel_launch(void* const* d_in, const int* in_sizes, int n_in,
                              void* d_out, int out_size, void* d_ws, size_t ws_size,
                              hipStream_t stream) {
  const float* x = (const float*)d_in[0];
  const float* w = (const float*)d_in[1];
  float* out = (float*)d_out;

  char* ws = (char*)d_ws;
  double* red = (double*)ws;                               // 256 * 8 B
  double* wsd = (double*)(ws + 2048);                      // 1 double
  float* ascale = (float*)(ws + 4096);                     // 16384 floats
  char* xq = (char*)(ws + 4096 + 65536);                   // 32 MiB
  char* wq = xq + (size_t)M_DIM * K_DIM;                   // 4 MiB

  k_wsum<<<256, 256, 0, stream>>>((const float4*)w, red);
  k_wscale<<<1, 256, 0, stream>>>(red, wsd);
  k_wquant<<<NW / 4 / 256, 256, 0, stream>>>((const float4*)w, wsd, (char4*)wq);
  k_xquant<<<M_DIM, 256, 0, stream>>>(x, ascale, xq);
  k_gemm<<<dim3(N_DIM / 256 * M_DIM / 256), 512, 0, stream>>>(xq, wq, ascale, wsd, out);
}

// Round 7
// 126.481 us; speedup vs baseline: 1.1906x; 1.0076x over previous
//
#include <hip/hip_runtime.h>
#include <hip/hip_bf16.h>

typedef int int4v __attribute__((ext_vector_type(4)));

#define K_DIM 2048
#define N_DIM 2048
#define M_DIM 16384
#define NW 4194304   // weight element count (2048*2048)
#define BKB 128      // K-step bytes per row (128 i8 elements)
#define NKT (K_DIM / BKB)   // 16 K-tiles

// ---------------- w_scale: deterministic 2-stage f64 abs-mean ----------------
__global__ void k_wsum(const float4* __restrict__ w4, double* __restrict__ red) {
  const int n4 = NW / 4;
  double s = 0.0;
  for (int i = blockIdx.x * blockDim.x + threadIdx.x; i < n4; i += gridDim.x * blockDim.x) {
    float4 v = w4[i];
    s += (double)fabsf(v.x) + (double)fabsf(v.y) + (double)fabsf(v.z) + (double)fabsf(v.w);
  }
  for (int o = 32; o; o >>= 1) s += __shfl_xor(s, o);
  __shared__ double sd[4];
  if ((threadIdx.x & 63) == 0) sd[threadIdx.x >> 6] = s;
  __syncthreads();
  if (threadIdx.x == 0) red[blockIdx.x] = (sd[0] + sd[1]) + (sd[2] + sd[3]);
}

__global__ void k_wscale(const double* __restrict__ red, double* __restrict__ wsd) {
  double s = red[threadIdx.x];                 // 256 threads, parallel
  for (int o = 32; o; o >>= 1) s += __shfl_xor(s, o);
  __shared__ double sd[4];
  if ((threadIdx.x & 63) == 0) sd[threadIdx.x >> 6] = s;
  __syncthreads();
  if (threadIdx.x == 0) {
    double m = ((sd[0] + sd[1]) + (sd[2] + sd[3])) / (double)NW;
    *wsd = (m > 1e-6) ? m : 1e-6;
  }
}

// ---------------- weight ternary quant -> int8 {-1,0,1} ----------------
__device__ __forceinline__ char wq1(float v, double ws) {
  double r = rint((double)v / ws);          // round-half-even, matches np.round
  r = fmin(fmax(r, -1.0), 1.0);
  return (char)(int)r;
}

__global__ void k_wquant(const float4* __restrict__ w4, const double* __restrict__ wsd,
                         char4* __restrict__ wq4) {
  int i = blockIdx.x * blockDim.x + threadIdx.x;
  if (i >= NW / 4) return;
  double ws = *wsd;
  float4 v = w4[i];
  char4 q;
  q.x = wq1(v.x, ws);
  q.y = wq1(v.y, ws);
  q.z = wq1(v.z, ws);
  q.w = wq1(v.w, ws);
  wq4[i] = q;
}

// ---------------- per-token absmax + int8 absmax quant ----------------
__device__ __forceinline__ char qi8(float v, double rr) {
  double q = rint((double)v * rr);
  q = fmin(fmax(q, -127.0), 127.0);
  return (char)(int)q;
}

__global__ void k_xquant(const float* __restrict__ x, float* __restrict__ ascale,
                         char* __restrict__ xq) {
  const int row = blockIdx.x;
  const int t = threadIdx.x;
  const float4* xr = (const float4*)(x + (size_t)row * K_DIM);
  float4 v0 = xr[t];
  float4 v1 = xr[t + 256];
  float m = fmaxf(fmaxf(fmaxf(fabsf(v0.x), fabsf(v0.y)), fmaxf(fabsf(v0.z), fabsf(v0.w))),
                  fmaxf(fmaxf(fabsf(v1.x), fabsf(v1.y)), fmaxf(fabsf(v1.z), fabsf(v1.w))));
  for (int o = 32; o; o >>= 1) m = fmaxf(m, __shfl_xor(m, o));
  __shared__ float sm[4];
  if ((t & 63) == 0) sm[t >> 6] = m;
  __syncthreads();
  float a = fmaxf(fmaxf(sm[0], sm[1]), fmaxf(sm[2], sm[3]));
  a = fmaxf(a, 1e-8f);
  if (t == 0) ascale[row] = a;
  double rr = 127.0 / (double)a;
  char4* qr4 = (char4*)(xq + (size_t)row * K_DIM);
  char4 a4, b4;
  a4.x = qi8(v0.x, rr); a4.y = qi8(v0.y, rr); a4.z = qi8(v0.z, rr); a4.w = qi8(v0.w, rr);
  b4.x = qi8(v1.x, rr); b4.y = qi8(v1.y, rr); b4.z = qi8(v1.z, rr); b4.w = qi8(v1.w, rr);
  qr4[t] = a4;
  qr4[t + 256] = b4;
}

// ---------------- GEMM: 256x256, 8 waves, m201-faithful 4-phase counted-vmcnt
__device__ __forceinline__ void gload16(const void* g, void* l) {
  __builtin_amdgcn_global_load_lds(
      (const __attribute__((address_space(1))) void*)g,
      (__attribute__((address_space(3))) void*)l, 16, 0, 0);
}

#define RD_A(DST, CA, MH, CO)                                               \
  _Pragma("unroll") for (int mf = 0; mf < 4; ++mf)                          \
    DST[mf] = *(const int4v*)((CA) + (rA + (MH)*64 + mf * 16) * 128 + (CO));

#define RD_B(DST, CB, CO)                                                   \
  _Pragma("unroll") for (int nf = 0; nf < 4; ++nf)                          \
    DST[nf] = *(const int4v*)((CB) + (rB + nf * 16) * 128 + (CO));

#define MM(MH, AF, BF)                                                      \
  __builtin_amdgcn_s_setprio(1);                                            \
  _Pragma("unroll") for (int mf = 0; mf < 4; ++mf)                          \
  _Pragma("unroll") for (int nf = 0; nf < 4; ++nf)                          \
    acc[(MH)*4 + mf][nf] = __builtin_amdgcn_mfma_i32_16x16x64_i8(           \
        AF[mf], BF[nf], acc[(MH)*4 + mf][nf], 0, 0, 0);                     \
  __builtin_amdgcn_s_setprio(0);

#define SBAR   __builtin_amdgcn_s_barrier()
#define LGKM0  asm volatile("s_waitcnt lgkmcnt(0)" ::: "memory")
#define VM2    asm volatile("s_waitcnt vmcnt(2)" ::: "memory")

// One K-tile = 4 phases (m201 shape). Staging: 2 gloads/phase, one tile ahead,
// order A0A2 / B0B1 / B2B3 / A1A3 (earliest-needed first). Counted vmcnt(2)
// gates before the CLOSING barrier of ph0 and ph3 only: FIFO retires all but
// the 2 newest loads; issuer-wait -> barrier -> read = cross-wave safe.
// Loads never drain to 0 in the main loop.
#define TILE(CA, CB, NA, NB, KT)                                            \
  {                                                                         \
    const char* An = Ab + (((KT) + 1) & (NKT - 1)) * BKB;                   \
    const char* Bn = Bb + (((KT) + 1) & (NKT - 1)) * BKB;                   \
    /* ph0: frags(MH0,co0) | stage A0,A2 | gate(A1A3 of this tile) */       \
    RD_A(af, CA, 0, co0);                                                   \
    RD_B(bf, CB, co0);                                                      \
    gload16(An + soff[0], (NA) + loff[0]);                                  \
    gload16(An + soff[2], (NA) + loff[2]);                                  \
    SBAR; LGKM0;                                                            \
    MM(0, af, bf);                                                          \
    VM2; SBAR;                                                              \
    /* ph1: frags(MH1,co0), B reused | stage B0,B1 */                       \
    RD_A(af, CA, 1, co0);                                                   \
    gload16(Bn + soff[0], (NB) + loff[0]);                                  \
    gload16(Bn + soff[1], (NB) + loff[1]);                                  \
    SBAR; LGKM0;                                                            \
    MM(1, af, bf);                                                          \
    SBAR;                                                                   \
    /* ph2: frags(MH0,co1) | stage B2,B3 */                                 \
    RD_A(af, CA, 0, co1);                                                   \
    RD_B(bf, CB, co1);                                                      \
    gload16(Bn + soff[2], (NB) + loff[2]);                                  \
    gload16(Bn + soff[3], (NB) + loff[3]);                                  \
    SBAR; LGKM0;                                                            \
    MM(0, af, bf);                                                          \
    SBAR;                                                                   \
    /* ph3: frags(MH1,co1) | stage A1,A3 | gate(next tile ph0 chunks) */    \
    RD_A(af, CA, 1, co1);                                                   \
    gload16(An + soff[1], (NA) + loff[1]);                                  \
    gload16(An + soff[3], (NA) + loff[3]);                                  \
    SBAR; LGKM0;                                                            \
    MM(1, af, bf);                                                          \
    VM2; SBAR;                                                              \
  }

__global__ __launch_bounds__(512, 1) void k_gemm(
    const char* __restrict__ xq, const char* __restrict__ wq,
    const float* __restrict__ ascale, const double* __restrict__ wsd,
    float* __restrict__ out) {
  __shared__ __align__(16) char lds[131072];
  char* lA0 = lds;            // 32 KB
  char* lB0 = lds + 32768;
  char* lA1 = lds + 65536;
  char* lB1 = lds + 98304;

  const int tid = threadIdx.x;
  const int l = tid & 63;
  const int wv = tid >> 6;        // 0..7
  const int wm = wv >> 2;         // M half
  const int wn = wv & 3;          // N quarter
  const int g = l >> 4, r16 = l & 15;

  // XCD-aware bijective swizzle: 512 blocks = 8 xcd * 64 chunk
  const int bid = blockIdx.x;
  const int logical = (bid & 7) * 64 + (bid >> 3);
  const int br = logical >> 3;    // 0..63  (M blocks)
  const int bc = logical & 7;     // 0..7   (N blocks)

  const char* Ab = xq + (size_t)br * 256 * K_DIM;
  const char* Bb = wq + (size_t)bc * 256 * K_DIM;

  // staging: LDS dest linear (global_load_lds constraint), source pre-swizzled.
  // chunk c = rows [64c, 64c+64) of the 256x128B operand tile (8 KB each).
  int soff[4], loff[4];
#pragma unroll
  for (int c = 0; c < 4; ++c) {
    int lb = c * 8192 + tid * 16;
    loff[c] = lb;
    int row = lb >> 7;
    int cb = lb & 127;
    soff[c] = row * K_DIM + (cb ^ ((row & 7) << 4));
  }

  // read-side swizzled column offsets (row&7 == r16&7 for all fragment rows)
  const int sw = (r16 & 7) << 4;
  const int co0 = (g * 16) ^ sw;        // k-slice 0
  const int co1 = (64 + g * 16) ^ sw;   // k-slice 1
  const int rA = wm * 128 + r16;
  const int rB = wn * 64 + r16;

  int4v acc[8][4];
#pragma unroll
  for (int mf = 0; mf < 8; ++mf)
#pragma unroll
    for (int nf = 0; nf < 4; ++nf) acc[mf][nf] = (int4v){0, 0, 0, 0};

  // prologue: stage tile 0 into buf0, drain, sync
#pragma unroll
  for (int c = 0; c < 4; ++c) gload16(Ab + soff[c], lA0 + loff[c]);
#pragma unroll
  for (int c = 0; c < 4; ++c) gload16(Bb + soff[c], lB0 + loff[c]);
  asm volatile("s_waitcnt vmcnt(0)" ::: "memory");
  SBAR;

  int4v af[4], bf[4];

  for (int kt = 0; kt < NKT; kt += 2) {
    TILE(lA0, lB0, lA1, lB1, kt);
    TILE(lA1, lB1, lA0, lB0, kt + 1);
  }

  // epilogue: y = acc * w_scale * (a_scale[t]/127); |acc| <= 127*2048 < 2^24 exact
  float wsf = (float)(*wsd);
  size_t trow0 = (size_t)br * 256 + wm * 128;
  int oc0 = bc * 256 + wn * 64;
#pragma unroll
  for (int mf = 0; mf < 8; ++mf) {
#pragma unroll
    for (int j = 0; j < 4; ++j) {
      size_t t = trow0 + mf * 16 + g * 4 + j;  // C/D: col=lane&15, row=(lane>>4)*4+reg
      float s = wsf * (ascale[t] / 127.0f);
      float* yr = out + t * (size_t)N_DIM + oc0;
#pragma unroll
      for (int nf = 0; nf < 4; ++nf) yr[nf * 16 + r16] = (float)acc[mf][nf][j] * s;
    }
  }
}

extern "C" void kernel_launch(void* const* d_in, const int* in_sizes, int n_in,
                              void* d_out, int out_size, void* d_ws, size_t ws_size,
                              hipStream_t stream) {
  const float* x = (const float*)d_in[0];
  const float* w = (const float*)d_in[1];
  float* out = (float*)d_out;

  char* ws = (char*)d_ws;
  double* red = (double*)ws;                               // 256 * 8 B
  double* wsd = (double*)(ws + 2048);                      // 1 double
  float* ascale = (float*)(ws + 4096);                     // 16384 floats
  char* xq = (char*)(ws + 4096 + 65536);                   // 32 MiB
  char* wq = xq + (size_t)M_DIM * K_DIM;                   // 4 MiB

  k_wsum<<<256, 256, 0, stream>>>((const float4*)w, red);
  k_wscale<<<1, 256, 0, stream>>>(red, wsd);
  k_wquant<<<NW / 4 / 256, 256, 0, stream>>>((const float4*)w, wsd, (char4*)wq);
  k_xquant<<<M_DIM, 256, 0, stream>>>(x, ascale, xq);
  k_gemm<<<dim3(N_DIM / 256 * M_DIM / 256), 512, 0, stream>>>(xq, wq, ascale, wsd, out);
}